// Round 9
// baseline (101.572 us; speedup 1.0000x reference)
//
#include <hip/hip_runtime.h>
#include <hip/hip_fp8.h>

// HardNetLoss: a = x[:8192], p = x[8192:], d_ij = sqrt((1 - a_i·p_j + 1e-6)*2)
// pos_i = d_ii ; neg_i = min(min_{j!=i} d_ji, min_{j!=i} d_ij)
// out = mean(relu(1 - neg + pos))
//
// R9: occupancy push. R8 (MX fp8 32x32x64, 64x128 wave tile) sat at
// 2 waves/SIMD (VGPR>128) with ~10us unhidden L2 latency. Now: 64x64 wave
// tile (acc 64 + frags 32 + misc <= 128 VGPR), __launch_bounds__(256,4)
// -> 4 waves/SIMD. Block 128x128 (2x2 waves), grid 4096, XCD swizzle
// (1.5 MB/XCD L2-resident). Same barrier-free direct-from-L2 K-loop.
// 32x32 C/D layout: col = lane&31, row = (reg&3)+8*(reg>>2)+4*(lane>>5).

#define CNT    8192
#define KDIM   256
#define BIGF   3.0e38f
#define SCALE1 0x7F7F7F7F            // 4x e8m0 bytes, each = 2^0

typedef float f32x4  __attribute__((ext_vector_type(4)));
typedef float f32x16 __attribute__((ext_vector_type(16)));
typedef int   v8i    __attribute__((ext_vector_type(8)));

union frag8 { uint4 q[2]; v8i v; };

__device__ __forceinline__ unsigned short f2bf(float f) {
    unsigned u = __float_as_uint(f);
    u += 0x7FFFu + ((u >> 16) & 1u);          // round-to-nearest-even
    return (unsigned short)(u >> 16);
}

__device__ __forceinline__ unsigned cvt4_fp8(float a, float b, float c, float d) {
#if __has_builtin(__builtin_amdgcn_cvt_pk_fp8_f32)
    unsigned v = __builtin_amdgcn_cvt_pk_fp8_f32(a, b, 0, false);
    v = __builtin_amdgcn_cvt_pk_fp8_f32(c, d, v, true);
    return v;
#else
    return (unsigned)__hip_fp8_e4m3(a).__x |
           ((unsigned)__hip_fp8_e4m3(b).__x << 8) |
           ((unsigned)__hip_fp8_e4m3(c).__x << 16) |
           ((unsigned)__hip_fp8_e4m3(d).__x << 24);
#endif
}

// ---------------- fast path ----------------

// x fp32 [16384][256] -> xb fp8, MX-fragment-packed. Chunk (rg32, kc64) is
// 2KB: half h holds j 0..15 (h=0) / 16..31 (h=1) of each lane's 32-k block;
// lane = (row%32) + 32*((col%64)/32). Thread T writes 16B at xb + T*16.
__global__ __launch_bounds__(256) void convert_mx_kernel(
    const float* __restrict__ x, unsigned char* __restrict__ xb,
    unsigned* __restrict__ mins)
{
    int T    = blockIdx.x * 256 + threadIdx.x;   // 262144 threads
    int lane = T & 63;
    int h    = (T >> 6) & 1;
    int c    = T >> 7;                           // chunk 0..2047
    int kc64 = c & 3;
    int rg   = c >> 2;                           // 32-row group
    int row  = rg * 32 + (lane & 31);
    int col0 = kc64 * 64 + (lane >> 5) * 32 + h * 16;
    const float* src = x + (size_t)row * KDIM + col0;
    float4 u0 = *(const float4*)(src);
    float4 u1 = *(const float4*)(src + 4);
    float4 u2 = *(const float4*)(src + 8);
    float4 u3 = *(const float4*)(src + 12);
    uint4 w;
    w.x = cvt4_fp8(u0.x, u0.y, u0.z, u0.w);
    w.y = cvt4_fp8(u1.x, u1.y, u1.z, u1.w);
    w.z = cvt4_fp8(u2.x, u2.y, u2.z, u2.w);
    w.w = cvt4_fp8(u3.x, u3.y, u3.z, u3.w);
    *(uint4*)(xb + (size_t)T * 16) = w;
    if (T < 2 * CNT) mins[T] = 0x7F7FFFFFu;      // FLT_MAX bits
}

// block tile 128(m) x 128(n); 4 waves 2x2; wave tile 64x64 of 32x32x64 MFMA.
#define TST 132                                   // T leading stride (f32)
__global__ __launch_bounds__(256, 4) void dist8_kernel(
    const unsigned char* __restrict__ Ab, const unsigned char* __restrict__ Pb,
    unsigned* __restrict__ g_rowmin, unsigned* __restrict__ g_colmin,
    float* __restrict__ g_pos)
{
    __shared__ float T[64 * TST];                // 33.8 KB (epilogue only)

    const int tid  = threadIdx.x;
    // XCD-aware swizzle: xcd gets a 16(bm) x 32(bn) region (0.5+1 MB in L2)
    const int l    = blockIdx.x;
    const int xcd  = l & 7;
    const int i    = l >> 3;                     // 0..511
    const int bm   = (xcd >> 1) * 16 + (i & 15); // 0..63
    const int bn   = (xcd & 1) * 32 + (i >> 4);  // 0..63

    const int wave = tid >> 6;
    const int lane = tid & 63;
    const int l31  = lane & 31;
    const int kh   = lane >> 5;                  // k-half / C-row-half selector
    const int wm   = wave >> 1;                  // 0..1 : m half
    const int wn   = wave & 1;                   // 0..1 : n half

    f32x16 acc[2][2];
    #pragma unroll
    for (int a = 0; a < 2; a++)
        #pragma unroll
        for (int b = 0; b < 2; b++)
            #pragma unroll
            for (int r = 0; r < 16; r++)
                acc[a][b][r] = 0.f;

    // chunk (rg32, kc64) = 2KB at (rg32*4 + kc64)*2048; lane slot +lane*16,
    // halves at +0 / +1024.
    const char* Abase = (const char*)Ab + lane * 16;
    const char* Pbase = (const char*)Pb + lane * 16;
    size_t a_off[2], b_off[2];
    #pragma unroll
    for (int mi = 0; mi < 2; mi++)
        a_off[mi] = (size_t)(bm * 4 + wm * 2 + mi) << 13;    // rg32 * 8192
    #pragma unroll
    for (int ni = 0; ni < 2; ni++)
        b_off[ni] = (size_t)(bn * 4 + wn * 2 + ni) << 13;

    // K-loop: 4 steps of K=64; 8 coalesced dwordx4 + 4 MFMA per step.
    #pragma unroll
    for (int kc = 0; kc < 4; kc++) {
        frag8 af[2], bf[2];
        #pragma unroll
        for (int mi = 0; mi < 2; mi++) {
            af[mi].q[0] = *(const uint4*)(Abase + a_off[mi] + kc * 2048);
            af[mi].q[1] = *(const uint4*)(Abase + a_off[mi] + kc * 2048 + 1024);
        }
        #pragma unroll
        for (int ni = 0; ni < 2; ni++) {
            bf[ni].q[0] = *(const uint4*)(Pbase + b_off[ni] + kc * 2048);
            bf[ni].q[1] = *(const uint4*)(Pbase + b_off[ni] + kc * 2048 + 1024);
        }
        #pragma unroll
        for (int mi = 0; mi < 2; mi++)
            #pragma unroll
            for (int ni = 0; ni < 2; ni++)
                acc[mi][ni] = __builtin_amdgcn_mfma_scale_f32_32x32x64_f8f6f4(
                    af[mi].v, bf[ni].v, acc[mi][ni],
                    0, 0,                 // cbsz = fp8 e4m3, blgp = fp8 e4m3
                    0, SCALE1,            // scale_a opsel, scale_a
                    0, SCALE1);           // scale_b opsel, scale_b
    }

    // ---- epilogue. C/D: col = l31, row = (reg&3) + 8*(reg>>2) + 4*kh.
    // local row rl = wm*64 + mi*32 + rowf(reg)   (0..127)
    // local col cl = wn*64 + ni*32 + l31         (0..127)

    if (bm == bn) {                              // diagonal block
        #pragma unroll
        for (int mi = 0; mi < 2; mi++)
            #pragma unroll
            for (int ni = 0; ni < 2; ni++)
                #pragma unroll
                for (int reg = 0; reg < 16; reg++) {
                    int rl = wm * 64 + mi * 32 + (reg & 3) + 8 * (reg >> 2) + 4 * kh;
                    int cl = wn * 64 + ni * 32 + l31;
                    if (cl == rl) {
                        g_pos[bm * 128 + rl] = (1.0f - acc[mi][ni][reg] + 1e-6f) * 2.0f;
                        acc[mi][ni][reg] = -BIGF;
                    }
                }
    }

    // col-direction (min over this wave's 64 rows => max s): fold + 1 shuffle
    #pragma unroll
    for (int ni = 0; ni < 2; ni++) {
        float v = -BIGF;
        #pragma unroll
        for (int mi = 0; mi < 2; mi++)
            #pragma unroll
            for (int reg = 0; reg < 16; reg++)
                v = fmaxf(v, acc[mi][ni][reg]);
        v = fmaxf(v, __shfl_xor(v, 32, 64));
        if (kh == 0) {
            float tt = fmaxf((1.0f - v + 1e-6f) * 2.0f, 0.0f);
            atomicMin(&g_colmin[bn * 128 + wn * 64 + ni * 32 + l31],
                      __float_as_uint(tt));
        }
    }

    // row-direction: fold over ni in-lane; reg&3-contiguous runs of 4 ->
    // f32x4 LDS transpose writes; waves write disjoint (entry, row) regions.
    const int entry = wn * 32 + l31;             // 0..63
    #pragma unroll
    for (int mi = 0; mi < 2; mi++)
        #pragma unroll
        for (int q = 0; q < 4; q++) {
            f32x4 v;
            #pragma unroll
            for (int rr = 0; rr < 4; rr++)
                v[rr] = fmaxf(acc[mi][0][q * 4 + rr], acc[mi][1][q * 4 + rr]);
            *(f32x4*)&T[entry * TST + wm * 64 + mi * 32 + q * 8 + kh * 4] = v;
        }
    __syncthreads();

    {
        int row  = tid & 127;
        int half = tid >> 7;                     // entries half*32 .. +31
        const float* Tb = &T[(half * 32) * TST + row];
        float v0 = Tb[0], v1 = Tb[TST];
        #pragma unroll
        for (int e = 2; e < 32; e += 2) {
            v0 = fmaxf(v0, Tb[e * TST]);
            v1 = fmaxf(v1, Tb[(e + 1) * TST]);
        }
        float v = fmaxf(v0, v1);
        float tt = fmaxf((1.0f - v + 1e-6f) * 2.0f, 0.0f);
        atomicMin(&g_rowmin[bm * 128 + row], __float_as_uint(tt));
    }
}

__global__ __launch_bounds__(1024) void finalize_t_kernel(
    const unsigned* __restrict__ rm, const unsigned* __restrict__ cm,
    const float* __restrict__ post, float* __restrict__ out)
{
    float local = 0.f;
    for (int i = threadIdx.x; i < CNT; i += 1024) {
        float t   = fminf(__uint_as_float(rm[i]), __uint_as_float(cm[i]));
        float neg = sqrtf(fmaxf(t, 0.f));
        float pos = sqrtf(fmaxf(post[i], 0.f));
        local += fmaxf(1.0f - neg + pos, 0.0f);
    }
    #pragma unroll
    for (int m = 1; m < 64; m <<= 1) local += __shfl_xor(local, m, 64);
    __shared__ float wsum[16];
    if ((threadIdx.x & 63) == 0) wsum[threadIdx.x >> 6] = local;
    __syncthreads();
    if (threadIdx.x == 0) {
        float s = 0.f;
        #pragma unroll
        for (int w = 0; w < 16; w++) s += wsum[w];
        out[0] = s * (1.0f / (float)CNT);
    }
}

// ---------------- fallback path (round-1, known passing; 96 KB ws) ----------------

#define BM 128
#define BN 128
#define BK 64
#define KST (BK + 8)

typedef __bf16 bf16x8 __attribute__((ext_vector_type(8)));

__global__ __launch_bounds__(256) void init_min_kernel(unsigned* buf, int n) {
    int i = blockIdx.x * 256 + threadIdx.x;
    if (i < n) buf[i] = 0x7F7FFFFFu;
}

__global__ __launch_bounds__(256) void dist_tile_kernel(
    const float* __restrict__ A, const float* __restrict__ P,
    unsigned* __restrict__ g_rowmin, unsigned* __restrict__ g_colmin,
    float* __restrict__ g_pos)
{
    __shared__ unsigned short As[BM * KST];
    __shared__ unsigned short Bs[BN * KST];
    __shared__ unsigned redrow[BM];
    __shared__ unsigned redcol[BN];

    const int tid  = threadIdx.x;
    const int bm   = blockIdx.y;
    const int bn   = blockIdx.x;
    const int wave = tid >> 6;
    const int lane = tid & 63;
    const int quad = lane >> 4;
    const int l15  = lane & 15;
    const int m_off = (wave >> 1) * 64;
    const int n_off = (wave & 1) * 64;

    if (tid < BM) redrow[tid] = 0x7F7FFFFFu;
    if (tid < BN) redcol[tid] = 0x7F7FFFFFu;

    f32x4 acc[4][4];
    #pragma unroll
    for (int i = 0; i < 4; i++)
        #pragma unroll
        for (int j = 0; j < 4; j++)
            acc[i][j] = (f32x4){0.f, 0.f, 0.f, 0.f};

    const int srow = tid >> 4;
    const int scol = tid & 15;

    for (int kc = 0; kc < KDIM / BK; kc++) {
        #pragma unroll
        for (int i = 0; i < 8; i++) {
            int r = srow + i * 16;
            float4 va = *(const float4*)(A + (size_t)(bm * BM + r) * KDIM + kc * BK + scol * 4);
            float4 vb = *(const float4*)(P + (size_t)(bn * BN + r) * KDIM + kc * BK + scol * 4);
            ushort4 wa, wb;
            wa.x = f2bf(va.x); wa.y = f2bf(va.y); wa.z = f2bf(va.z); wa.w = f2bf(va.w);
            wb.x = f2bf(vb.x); wb.y = f2bf(vb.y); wb.z = f2bf(vb.z); wb.w = f2bf(vb.w);
            *(ushort4*)(&As[r * KST + scol * 4]) = wa;
            *(ushort4*)(&Bs[r * KST + scol * 4]) = wb;
        }
        __syncthreads();
        #pragma unroll
        for (int ks = 0; ks < BK / 32; ks++) {
            bf16x8 af[4], bfr[4];
            #pragma unroll
            for (int mi = 0; mi < 4; mi++)
                af[mi] = *(const bf16x8*)(&As[(m_off + mi * 16 + l15) * KST + ks * 32 + quad * 8]);
            #pragma unroll
            for (int ni = 0; ni < 4; ni++)
                bfr[ni] = *(const bf16x8*)(&Bs[(n_off + ni * 16 + l15) * KST + ks * 32 + quad * 8]);
            #pragma unroll
            for (int mi = 0; mi < 4; mi++)
                #pragma unroll
                for (int ni = 0; ni < 4; ni++)
                    acc[mi][ni] = __builtin_amdgcn_mfma_f32_16x16x32_bf16(
                        af[mi], bfr[ni], acc[mi][ni], 0, 0, 0);
        }
        __syncthreads();
    }

    float rmin[4][4], cmin[4];
    #pragma unroll
    for (int mi = 0; mi < 4; mi++)
        #pragma unroll
        for (int r = 0; r < 4; r++) rmin[mi][r] = BIGF;
    #pragma unroll
    for (int ni = 0; ni < 4; ni++) cmin[ni] = BIGF;

    const int grow0 = bm * BM + m_off + quad * 4;
    const int gcol0 = bn * BN + n_off + l15;

    #pragma unroll
    for (int mi = 0; mi < 4; mi++)
        #pragma unroll
        for (int ni = 0; ni < 4; ni++) {
            int gcol = gcol0 + ni * 16;
            #pragma unroll
            for (int r = 0; r < 4; r++) {
                int grow = grow0 + mi * 16 + r;
                float s = acc[mi][ni][r];
                float d = sqrtf((1.0f - s + 1e-6f) * 2.0f);
                float dm = d;
                if (grow == gcol) { g_pos[grow] = d; dm = BIGF; }
                rmin[mi][r] = fminf(rmin[mi][r], dm);
                cmin[ni]    = fminf(cmin[ni], dm);
            }
        }

    #pragma unroll
    for (int mi = 0; mi < 4; mi++)
        #pragma unroll
        for (int r = 0; r < 4; r++) {
            float v = rmin[mi][r];
            v = fminf(v, __shfl_xor(v, 1, 64));
            v = fminf(v, __shfl_xor(v, 2, 64));
            v = fminf(v, __shfl_xor(v, 4, 64));
            v = fminf(v, __shfl_xor(v, 8, 64));
            rmin[mi][r] = v;
        }
    #pragma unroll
    for (int ni = 0; ni < 4; ni++) {
        float v = cmin[ni];
        v = fminf(v, __shfl_xor(v, 16, 64));
        v = fminf(v, __shfl_xor(v, 32, 64));
        cmin[ni] = v;
    }

    if (l15 == 0) {
        #pragma unroll
        for (int mi = 0; mi < 4; mi++)
            #pragma unroll
            for (int r = 0; r < 4; r++)
                atomicMin(&redrow[m_off + mi * 16 + quad * 4 + r],
                          __float_as_uint(rmin[mi][r]));
    }
    if (quad == 0) {
        #pragma unroll
        for (int ni = 0; ni < 4; ni++)
            atomicMin(&redcol[n_off + ni * 16 + l15], __float_as_uint(cmin[ni]));
    }
    __syncthreads();

    if (tid < 128) atomicMin(&g_rowmin[bm * BM + tid], redrow[tid]);
    else           atomicMin(&g_colmin[bn * BN + (tid - 128)], redcol[tid - 128]);
}

__global__ __launch_bounds__(1024) void finalize_kernel(
    const unsigned* __restrict__ g_rowmin, const unsigned* __restrict__ g_colmin,
    const float* __restrict__ g_pos, float* __restrict__ out)
{
    float local = 0.f;
    for (int i = threadIdx.x; i < CNT; i += 1024) {
        float neg = fminf(__uint_as_float(g_rowmin[i]), __uint_as_float(g_colmin[i]));
        float v = 1.0f - neg + g_pos[i];
        local += fmaxf(v, 0.0f);
    }
    #pragma unroll
    for (int m = 1; m < 64; m <<= 1) local += __shfl_xor(local, m, 64);
    __shared__ float wsum[16];
    if ((threadIdx.x & 63) == 0) wsum[threadIdx.x >> 6] = local;
    __syncthreads();
    if (threadIdx.x == 0) {
        float s = 0.f;
        #pragma unroll
        for (int w = 0; w < 16; w++) s += wsum[w];
        out[0] = s * (1.0f / (float)CNT);
    }
}

// ---------------- host ----------------

extern "C" void kernel_launch(void* const* d_in, const int* in_sizes, int n_in,
                              void* d_out, int out_size, void* d_ws, size_t ws_size,
                              hipStream_t stream) {
    const float* x = (const float*)d_in[0];
    float* out = (float*)d_out;

    const size_t fp8_bytes = (size_t)2 * CNT * KDIM;        // 4,194,304
    const size_t need = fp8_bytes + (size_t)2 * CNT * 4 + (size_t)CNT * 4;

    if (ws_size >= need) {
        unsigned char* xb   = (unsigned char*)d_ws;
        unsigned*      mins = (unsigned*)((char*)d_ws + fp8_bytes);
        float*         pos  = (float*)(mins + 2 * CNT);
        convert_mx_kernel<<<dim3(1024), dim3(256), 0, stream>>>(x, xb, mins);
        dist8_kernel<<<dim3(4096), dim3(256), 0, stream>>>(
            xb, xb + (size_t)CNT * KDIM, mins, mins + CNT, pos);
        finalize_t_kernel<<<dim3(1), dim3(1024), 0, stream>>>(mins, mins + CNT, pos, out);
    } else {
        unsigned* rowmin = (unsigned*)d_ws;
        unsigned* colmin = rowmin + CNT;
        float*    pos    = (float*)(colmin + CNT);
        init_min_kernel<<<dim3(2 * CNT / 256), dim3(256), 0, stream>>>(rowmin, 2 * CNT);
        dist_tile_kernel<<<dim3(CNT / BN, CNT / BM), dim3(256), 0, stream>>>(
            x, x + (size_t)CNT * KDIM, rowmin, colmin, pos);
        finalize_kernel<<<dim3(1), dim3(1024), 0, stream>>>(rowmin, colmin, pos, out);
    }
}

// Round 10
// 92.179 us; speedup vs baseline: 1.1019x; 1.1019x over previous
//
#include <hip/hip_runtime.h>
#include <hip/hip_fp8.h>

// HardNetLoss: a = x[:8192], p = x[8192:], d_ij = sqrt((1 - a_i·p_j + 1e-6)*2)
// pos_i = d_ii ; neg_i = min(min_{j!=i} d_ji, min_{j!=i} d_ij)
// out = mean(relu(1 - neg + pos))
//
// R10: revert to R8 (64x128 wave tile, MX fp8 32x32x64 — best: 93.0 us;
// R9's 64x64 tile regressed via +33% feed bytes) + explicit depth-1
// register double-buffer in the K-loop: load kc+1's 12 fragments before
// kc's 8 MFMAs. VGPR ~236 <= 256 keeps 2 waves/SIMD.
// 32x32 C/D layout: col = lane&31, row = (reg&3)+8*(reg>>2)+4*(lane>>5).

#define CNT    8192
#define KDIM   256
#define BIGF   3.0e38f
#define SCALE1 0x7F7F7F7F            // 4x e8m0 bytes, each = 2^0

typedef float f32x4  __attribute__((ext_vector_type(4)));
typedef float f32x16 __attribute__((ext_vector_type(16)));
typedef int   v8i    __attribute__((ext_vector_type(8)));

union frag8 { uint4 q[2]; v8i v; };

__device__ __forceinline__ unsigned short f2bf(float f) {
    unsigned u = __float_as_uint(f);
    u += 0x7FFFu + ((u >> 16) & 1u);          // round-to-nearest-even
    return (unsigned short)(u >> 16);
}

__device__ __forceinline__ unsigned cvt4_fp8(float a, float b, float c, float d) {
#if __has_builtin(__builtin_amdgcn_cvt_pk_fp8_f32)
    unsigned v = __builtin_amdgcn_cvt_pk_fp8_f32(a, b, 0, false);
    v = __builtin_amdgcn_cvt_pk_fp8_f32(c, d, v, true);
    return v;
#else
    return (unsigned)__hip_fp8_e4m3(a).__x |
           ((unsigned)__hip_fp8_e4m3(b).__x << 8) |
           ((unsigned)__hip_fp8_e4m3(c).__x << 16) |
           ((unsigned)__hip_fp8_e4m3(d).__x << 24);
#endif
}

// ---------------- fast path ----------------

// x fp32 [16384][256] -> xb fp8, MX-fragment-packed. Chunk (rg32, kc64) is
// 2KB: half h holds j 0..15 (h=0) / 16..31 (h=1) of each lane's 32-k block;
// lane = (row%32) + 32*((col%64)/32). Thread T writes 16B at xb + T*16.
__global__ __launch_bounds__(256) void convert_mx_kernel(
    const float* __restrict__ x, unsigned char* __restrict__ xb,
    unsigned* __restrict__ mins)
{
    int T    = blockIdx.x * 256 + threadIdx.x;   // 262144 threads
    int lane = T & 63;
    int h    = (T >> 6) & 1;
    int c    = T >> 7;                           // chunk 0..2047
    int kc64 = c & 3;
    int rg   = c >> 2;                           // 32-row group
    int row  = rg * 32 + (lane & 31);
    int col0 = kc64 * 64 + (lane >> 5) * 32 + h * 16;
    const float* src = x + (size_t)row * KDIM + col0;
    float4 u0 = *(const float4*)(src);
    float4 u1 = *(const float4*)(src + 4);
    float4 u2 = *(const float4*)(src + 8);
    float4 u3 = *(const float4*)(src + 12);
    uint4 w;
    w.x = cvt4_fp8(u0.x, u0.y, u0.z, u0.w);
    w.y = cvt4_fp8(u1.x, u1.y, u1.z, u1.w);
    w.z = cvt4_fp8(u2.x, u2.y, u2.z, u2.w);
    w.w = cvt4_fp8(u3.x, u3.y, u3.z, u3.w);
    *(uint4*)(xb + (size_t)T * 16) = w;
    if (T < 2 * CNT) mins[T] = 0x7F7FFFFFu;      // FLT_MAX bits
}

// block tile 128(m) x 256(n); 4 waves 2x2; wave tile 64x128 of 32x32x64 MFMA.
#define TST 136                                   // T leading stride (f32)
__global__ __launch_bounds__(256, 2) void dist9_kernel(
    const unsigned char* __restrict__ Ab, const unsigned char* __restrict__ Pb,
    unsigned* __restrict__ g_rowmin, unsigned* __restrict__ g_colmin,
    float* __restrict__ g_pos)
{
    __shared__ float T[64 * TST];                // 34.8 KB (epilogue only)

    const int tid  = threadIdx.x;
    // XCD-aware swizzle: 8 regions of 16x16 blocks
    const int l    = blockIdx.x;
    const int xcd  = l & 7;
    const int i    = l >> 3;                     // 0..255
    const int bm   = (xcd >> 1) * 16 + (i & 15); // 0..63
    const int bn   = (xcd & 1) * 16 + (i >> 4);  // 0..31

    const int wave = tid >> 6;
    const int lane = tid & 63;
    const int l31  = lane & 31;
    const int kh   = lane >> 5;                  // k-half / C-row-half selector
    const int wm   = wave >> 1;                  // 0..1 : m half
    const int wn   = wave & 1;                   // 0..1 : n half

    f32x16 acc[2][4];
    #pragma unroll
    for (int a = 0; a < 2; a++)
        #pragma unroll
        for (int b = 0; b < 4; b++)
            #pragma unroll
            for (int r = 0; r < 16; r++)
                acc[a][b][r] = 0.f;

    // chunk (rg32, kc64) = 2KB at (rg32*4 + kc64)*2048; lane slot +lane*16,
    // halves at +0 / +1024.
    const char* Abase = (const char*)Ab + lane * 16;
    const char* Pbase = (const char*)Pb + lane * 16;
    size_t a_off[2], b_off[4];
    #pragma unroll
    for (int mi = 0; mi < 2; mi++)
        a_off[mi] = (size_t)(bm * 4 + wm * 2 + mi) << 13;    // rg32 * 8192
    #pragma unroll
    for (int ni = 0; ni < 4; ni++)
        b_off[ni] = (size_t)(bn * 8 + wn * 4 + ni) << 13;

    // K-loop: 4 steps of K=64; explicit depth-1 register double-buffer:
    // kc+1's 12 dwordx4 loads issue before kc's 8 MFMAs.
    frag8 ca[2], cb[4], na[2], nb[4];
    #pragma unroll
    for (int mi = 0; mi < 2; mi++) {
        ca[mi].q[0] = *(const uint4*)(Abase + a_off[mi]);
        ca[mi].q[1] = *(const uint4*)(Abase + a_off[mi] + 1024);
    }
    #pragma unroll
    for (int ni = 0; ni < 4; ni++) {
        cb[ni].q[0] = *(const uint4*)(Pbase + b_off[ni]);
        cb[ni].q[1] = *(const uint4*)(Pbase + b_off[ni] + 1024);
    }
    #pragma unroll
    for (int kc = 0; kc < 4; kc++) {
        if (kc < 3) {
            #pragma unroll
            for (int mi = 0; mi < 2; mi++) {
                na[mi].q[0] = *(const uint4*)(Abase + a_off[mi] + (kc + 1) * 2048);
                na[mi].q[1] = *(const uint4*)(Abase + a_off[mi] + (kc + 1) * 2048 + 1024);
            }
            #pragma unroll
            for (int ni = 0; ni < 4; ni++) {
                nb[ni].q[0] = *(const uint4*)(Pbase + b_off[ni] + (kc + 1) * 2048);
                nb[ni].q[1] = *(const uint4*)(Pbase + b_off[ni] + (kc + 1) * 2048 + 1024);
            }
        }
        #pragma unroll
        for (int mi = 0; mi < 2; mi++)
            #pragma unroll
            for (int ni = 0; ni < 4; ni++)
                acc[mi][ni] = __builtin_amdgcn_mfma_scale_f32_32x32x64_f8f6f4(
                    ca[mi].v, cb[ni].v, acc[mi][ni],
                    0, 0,                 // cbsz = fp8 e4m3, blgp = fp8 e4m3
                    0, SCALE1,            // scale_a opsel, scale_a
                    0, SCALE1);           // scale_b opsel, scale_b
        if (kc < 3) {
            #pragma unroll
            for (int mi = 0; mi < 2; mi++) ca[mi] = na[mi];
            #pragma unroll
            for (int ni = 0; ni < 4; ni++) cb[ni] = nb[ni];
        }
    }

    // ---- epilogue. C/D: col = l31, row = (reg&3) + 8*(reg>>2) + 4*kh.
    // local row rl = wm*64 + mi*32 + rowf(reg)   (0..127)
    // local col cl = wn*128 + ni*32 + l31        (0..255)

    if ((bm >> 1) == bn) {                       // diagonal band
        const int dstart = (bm & 1) * 128;
        #pragma unroll
        for (int mi = 0; mi < 2; mi++)
            #pragma unroll
            for (int ni = 0; ni < 4; ni++)
                #pragma unroll
                for (int reg = 0; reg < 16; reg++) {
                    int rl = wm * 64 + mi * 32 + (reg & 3) + 8 * (reg >> 2) + 4 * kh;
                    int cl = wn * 128 + ni * 32 + l31;
                    if (cl == rl + dstart) {
                        g_pos[bm * 128 + rl] = (1.0f - acc[mi][ni][reg] + 1e-6f) * 2.0f;
                        acc[mi][ni][reg] = -BIGF;
                    }
                }
    }

    // col-direction (min over rows => max s): in-lane fold + 1 shuffle (kh)
    #pragma unroll
    for (int ni = 0; ni < 4; ni++) {
        float v = -BIGF;
        #pragma unroll
        for (int mi = 0; mi < 2; mi++)
            #pragma unroll
            for (int reg = 0; reg < 16; reg++)
                v = fmaxf(v, acc[mi][ni][reg]);
        v = fmaxf(v, __shfl_xor(v, 32, 64));
        if (kh == 0) {
            float tt = fmaxf((1.0f - v + 1e-6f) * 2.0f, 0.0f);
            atomicMin(&g_colmin[bn * 256 + wn * 128 + ni * 32 + l31],
                      __float_as_uint(tt));
        }
    }

    // row-direction: fold over ni in-lane; rows come in reg&3-contiguous runs
    // of 4 -> f32x4 LDS transpose writes; waves write disjoint (entry,row).
    const int entry = wn * 32 + l31;             // 0..63
    #pragma unroll
    for (int mi = 0; mi < 2; mi++)
        #pragma unroll
        for (int q = 0; q < 4; q++) {
            f32x4 v;
            #pragma unroll
            for (int rr = 0; rr < 4; rr++) {
                float m = acc[mi][0][q * 4 + rr];
                #pragma unroll
                for (int ni = 1; ni < 4; ni++)
                    m = fmaxf(m, acc[mi][ni][q * 4 + rr]);
                v[rr] = m;
            }
            *(f32x4*)&T[entry * TST + wm * 64 + mi * 32 + q * 8 + kh * 4] = v;
        }
    __syncthreads();

    if (tid < 128) {
        int row = tid;
        float v0 = T[row], v1 = T[TST + row];
        #pragma unroll
        for (int e = 2; e < 64; e += 2) {
            v0 = fmaxf(v0, T[e * TST + row]);
            v1 = fmaxf(v1, T[(e + 1) * TST + row]);
        }
        float v = fmaxf(v0, v1);
        float tt = fmaxf((1.0f - v + 1e-6f) * 2.0f, 0.0f);
        atomicMin(&g_rowmin[bm * 128 + row], __float_as_uint(tt));
    }
}

__global__ __launch_bounds__(1024) void finalize_t_kernel(
    const unsigned* __restrict__ rm, const unsigned* __restrict__ cm,
    const float* __restrict__ post, float* __restrict__ out)
{
    float local = 0.f;
    for (int i = threadIdx.x; i < CNT; i += 1024) {
        float t   = fminf(__uint_as_float(rm[i]), __uint_as_float(cm[i]));
        float neg = sqrtf(fmaxf(t, 0.f));
        float pos = sqrtf(fmaxf(post[i], 0.f));
        local += fmaxf(1.0f - neg + pos, 0.0f);
    }
    #pragma unroll
    for (int m = 1; m < 64; m <<= 1) local += __shfl_xor(local, m, 64);
    __shared__ float wsum[16];
    if ((threadIdx.x & 63) == 0) wsum[threadIdx.x >> 6] = local;
    __syncthreads();
    if (threadIdx.x == 0) {
        float s = 0.f;
        #pragma unroll
        for (int w = 0; w < 16; w++) s += wsum[w];
        out[0] = s * (1.0f / (float)CNT);
    }
}

// ---------------- fallback path (round-1, known passing; 96 KB ws) ----------------

#define BM 128
#define BN 128
#define BK 64
#define KST (BK + 8)

typedef __bf16 bf16x8 __attribute__((ext_vector_type(8)));

__global__ __launch_bounds__(256) void init_min_kernel(unsigned* buf, int n) {
    int i = blockIdx.x * 256 + threadIdx.x;
    if (i < n) buf[i] = 0x7F7FFFFFu;
}

__global__ __launch_bounds__(256) void dist_tile_kernel(
    const float* __restrict__ A, const float* __restrict__ P,
    unsigned* __restrict__ g_rowmin, unsigned* __restrict__ g_colmin,
    float* __restrict__ g_pos)
{
    __shared__ unsigned short As[BM * KST];
    __shared__ unsigned short Bs[BN * KST];
    __shared__ unsigned redrow[BM];
    __shared__ unsigned redcol[BN];

    const int tid  = threadIdx.x;
    const int bm   = blockIdx.y;
    const int bn   = blockIdx.x;
    const int wave = tid >> 6;
    const int lane = tid & 63;
    const int quad = lane >> 4;
    const int l15  = lane & 15;
    const int m_off = (wave >> 1) * 64;
    const int n_off = (wave & 1) * 64;

    if (tid < BM) redrow[tid] = 0x7F7FFFFFu;
    if (tid < BN) redcol[tid] = 0x7F7FFFFFu;

    f32x4 acc[4][4];
    #pragma unroll
    for (int i = 0; i < 4; i++)
        #pragma unroll
        for (int j = 0; j < 4; j++)
            acc[i][j] = (f32x4){0.f, 0.f, 0.f, 0.f};

    const int srow = tid >> 4;
    const int scol = tid & 15;

    for (int kc = 0; kc < KDIM / BK; kc++) {
        #pragma unroll
        for (int i = 0; i < 8; i++) {
            int r = srow + i * 16;
            float4 va = *(const float4*)(A + (size_t)(bm * BM + r) * KDIM + kc * BK + scol * 4);
            float4 vb = *(const float4*)(P + (size_t)(bn * BN + r) * KDIM + kc * BK + scol * 4);
            ushort4 wa, wb;
            wa.x = f2bf(va.x); wa.y = f2bf(va.y); wa.z = f2bf(va.z); wa.w = f2bf(va.w);
            wb.x = f2bf(vb.x); wb.y = f2bf(vb.y); wb.z = f2bf(vb.z); wb.w = f2bf(vb.w);
            *(ushort4*)(&As[r * KST + scol * 4]) = wa;
            *(ushort4*)(&Bs[r * KST + scol * 4]) = wb;
        }
        __syncthreads();
        #pragma unroll
        for (int ks = 0; ks < BK / 32; ks++) {
            bf16x8 af[4], bfr[4];
            #pragma unroll
            for (int mi = 0; mi < 4; mi++)
                af[mi] = *(const bf16x8*)(&As[(m_off + mi * 16 + l15) * KST + ks * 32 + quad * 8]);
            #pragma unroll
            for (int ni = 0; ni < 4; ni++)
                bfr[ni] = *(const bf16x8*)(&Bs[(n_off + ni * 16 + l15) * KST + ks * 32 + quad * 8]);
            #pragma unroll
            for (int mi = 0; mi < 4; mi++)
                #pragma unroll
                for (int ni = 0; ni < 4; ni++)
                    acc[mi][ni] = __builtin_amdgcn_mfma_f32_16x16x32_bf16(
                        af[mi], bfr[ni], acc[mi][ni], 0, 0, 0);
        }
        __syncthreads();
    }

    float rmin[4][4], cmin[4];
    #pragma unroll
    for (int mi = 0; mi < 4; mi++)
        #pragma unroll
        for (int r = 0; r < 4; r++) rmin[mi][r] = BIGF;
    #pragma unroll
    for (int ni = 0; ni < 4; ni++) cmin[ni] = BIGF;

    const int grow0 = bm * BM + m_off + quad * 4;
    const int gcol0 = bn * BN + n_off + l15;

    #pragma unroll
    for (int mi = 0; mi < 4; mi++)
        #pragma unroll
        for (int ni = 0; ni < 4; ni++) {
            int gcol = gcol0 + ni * 16;
            #pragma unroll
            for (int r = 0; r < 4; r++) {
                int grow = grow0 + mi * 16 + r;
                float s = acc[mi][ni][r];
                float d = sqrtf((1.0f - s + 1e-6f) * 2.0f);
                float dm = d;
                if (grow == gcol) { g_pos[grow] = d; dm = BIGF; }
                rmin[mi][r] = fminf(rmin[mi][r], dm);
                cmin[ni]    = fminf(cmin[ni], dm);
            }
        }

    #pragma unroll
    for (int mi = 0; mi < 4; mi++)
        #pragma unroll
        for (int r = 0; r < 4; r++) {
            float v = rmin[mi][r];
            v = fminf(v, __shfl_xor(v, 1, 64));
            v = fminf(v, __shfl_xor(v, 2, 64));
            v = fminf(v, __shfl_xor(v, 4, 64));
            v = fminf(v, __shfl_xor(v, 8, 64));
            rmin[mi][r] = v;
        }
    #pragma unroll
    for (int ni = 0; ni < 4; ni++) {
        float v = cmin[ni];
        v = fminf(v, __shfl_xor(v, 16, 64));
        v = fminf(v, __shfl_xor(v, 32, 64));
        cmin[ni] = v;
    }

    if (l15 == 0) {
        #pragma unroll
        for (int mi = 0; mi < 4; mi++)
            #pragma unroll
            for (int r = 0; r < 4; r++)
                atomicMin(&redrow[m_off + mi * 16 + quad * 4 + r],
                          __float_as_uint(rmin[mi][r]));
    }
    if (quad == 0) {
        #pragma unroll
        for (int ni = 0; ni < 4; ni++)
            atomicMin(&redcol[n_off + ni * 16 + l15], __float_as_uint(cmin[ni]));
    }
    __syncthreads();

    if (tid < 128) atomicMin(&g_rowmin[bm * BM + tid], redrow[tid]);
    else           atomicMin(&g_colmin[bn * BN + (tid - 128)], redcol[tid - 128]);
}

__global__ __launch_bounds__(1024) void finalize_kernel(
    const unsigned* __restrict__ g_rowmin, const unsigned* __restrict__ g_colmin,
    const float* __restrict__ g_pos, float* __restrict__ out)
{
    float local = 0.f;
    for (int i = threadIdx.x; i < CNT; i += 1024) {
        float neg = fminf(__uint_as_float(g_rowmin[i]), __uint_as_float(g_colmin[i]));
        float v = 1.0f - neg + g_pos[i];
        local += fmaxf(v, 0.0f);
    }
    #pragma unroll
    for (int m = 1; m < 64; m <<= 1) local += __shfl_xor(local, m, 64);
    __shared__ float wsum[16];
    if ((threadIdx.x & 63) == 0) wsum[threadIdx.x >> 6] = local;
    __syncthreads();
    if (threadIdx.x == 0) {
        float s = 0.f;
        #pragma unroll
        for (int w = 0; w < 16; w++) s += wsum[w];
        out[0] = s * (1.0f / (float)CNT);
    }
}

// ---------------- host ----------------

extern "C" void kernel_launch(void* const* d_in, const int* in_sizes, int n_in,
                              void* d_out, int out_size, void* d_ws, size_t ws_size,
                              hipStream_t stream) {
    const float* x = (const float*)d_in[0];
    float* out = (float*)d_out;

    const size_t fp8_bytes = (size_t)2 * CNT * KDIM;        // 4,194,304
    const size_t need = fp8_bytes + (size_t)2 * CNT * 4 + (size_t)CNT * 4;

    if (ws_size >= need) {
        unsigned char* xb   = (unsigned char*)d_ws;
        unsigned*      mins = (unsigned*)((char*)d_ws + fp8_bytes);
        float*         pos  = (float*)(mins + 2 * CNT);
        convert_mx_kernel<<<dim3(1024), dim3(256), 0, stream>>>(x, xb, mins);
        dist9_kernel<<<dim3(2048), dim3(256), 0, stream>>>(
            xb, xb + (size_t)CNT * KDIM, mins, mins + CNT, pos);
        finalize_t_kernel<<<dim3(1), dim3(1024), 0, stream>>>(mins, mins + CNT, pos, out);
    } else {
        unsigned* rowmin = (unsigned*)d_ws;
        unsigned* colmin = rowmin + CNT;
        float*    pos    = (float*)(colmin + CNT);
        init_min_kernel<<<dim3(2 * CNT / 256), dim3(256), 0, stream>>>(rowmin, 2 * CNT);
        dist_tile_kernel<<<dim3(CNT / BN, CNT / BM), dim3(256), 0, stream>>>(
            x, x + (size_t)CNT * KDIM, rowmin, colmin, pos);
        finalize_kernel<<<dim3(1), dim3(1024), 0, stream>>>(rowmin, colmin, pos, out);
    }
}